// Round 4
// baseline (429.447 us; speedup 1.0000x reference)
//
#include <hip/hip_runtime.h>

#define N_NODES 262144
#define BGRAPHS 1024
#define NPG 256
#define LATENT 256
#define HIDDEN 512
#define BM 128
#define NSTEPS 48

typedef unsigned short ushort_t;
typedef __attribute__((ext_vector_type(4))) float  f32x4;
typedef __attribute__((ext_vector_type(8))) short  short8;
typedef __attribute__((ext_vector_type(4))) int    int4v;
typedef __attribute__((ext_vector_type(2))) unsigned int uint2v;
typedef __attribute__((ext_vector_type(4))) float  float4v;

#define GLOBAL_AS __attribute__((address_space(1)))
#define LDS_AS __attribute__((address_space(3)))

__device__ __forceinline__ unsigned int f2bf(float f) {
  union { float f; unsigned int u; } v; v.f = f;
  unsigned int u = v.u;
  return (u + 0x7fffu + ((u >> 16) & 1u)) >> 16;
}
__device__ __forceinline__ float silu_f(float x) { return x / (1.0f + __expf(-x)); }

// ---------------------------------------------------------------------------
// Weight prep. Image layout per tile (t, half): 16 KB contiguous =
// [p 0..3][n' 0..255][8 bf16], k = t*32 + p*8 + e, n = half*256 + n'.
// Tile order: [t][half]. W0: 16 tiles, W1: 32 tiles.
// ---------------------------------------------------------------------------
__global__ void prep_weights(const float* __restrict__ W0, const float* __restrict__ W1,
                             ushort_t* __restrict__ W0pre, ushort_t* __restrict__ W1pre) {
  int c = blockIdx.x * 256 + threadIdx.x;   // 49152 cells of 8 elems
  const int C0 = 16384;
  const float* src;
  ushort_t* dst;
  int cc;
  if (c < C0) { src = W0; dst = W0pre; cc = c; }
  else        { src = W1; dst = W1pre; cc = c - C0; }
  int np = cc & 255;
  int p = (cc >> 8) & 3;
  int hf = (cc >> 10) & 1;
  int t = cc >> 11;
  int n = hf * 256 + np;
  int kb = t * 32 + p * 8;
  unsigned w[4];
#pragma unroll
  for (int j = 0; j < 4; ++j) {
    unsigned lo = f2bf(src[(size_t)(kb + 2 * j) * HIDDEN + n]);
    unsigned hi = f2bf(src[(size_t)(kb + 2 * j + 1) * HIDDEN + n]);
    w[j] = lo | (hi << 16);
  }
  *(int4v*)(dst + (size_t)cc * 8) = *(int4v*)w;
}

__device__ __forceinline__ const ushort_t* wsrc(const ushort_t* W0p, const ushort_t* W1p, int s) {
  return (s < 16) ? W0p + (((s & 7) * 2 + (s >> 3)) * 8192)
                  : W1p + ((((s - 16) & 15) * 2 + ((s - 16) >> 4)) * 8192);
}

__device__ __forceinline__ void stage16(const ushort_t* src, char* dst, int wid, int lane) {
#pragma unroll
  for (int j = 0; j < 2; ++j) {
    const char* g = (const char*)src + j * 8192 + wid * 1024 + lane * 16;
    char* l = dst + j * 8192 + wid * 1024;
    __builtin_amdgcn_global_load_lds((const GLOBAL_AS void*)g, (LDS_AS void*)l, 16, 0, 0);
  }
}

// ---------------------------------------------------------------------------
// Fused MLP. Block: M=128 rows, N processed in two 256-halves per GEMM.
// 8 waves, wave tile 64m x 64n, acc[4][4]. Weights: 2x16KB LDS dbuf fed by
// global_load_lds, counted vmcnt(2) pipeline (never drained in-loop).
// h1 lives in Hc [128 rows][1024 B] low+high; bf16 A-tiles parked in Hc high
// halves during GEMM1 (freed exactly when epilogue1-half1 overwrites them).
// ---------------------------------------------------------------------------
__global__ __launch_bounds__(512) void fused_mlp(
    const float* __restrict__ feat, const ushort_t* __restrict__ W0pre,
    const ushort_t* __restrict__ W1pre, const float* __restrict__ b0,
    const float* __restrict__ b1, const float* __restrict__ W2,
    const float* __restrict__ b2, float* __restrict__ pred) {
  __shared__ __align__(16) char smem[163840];
  char* Wbuf = smem;              // 2 x 16 KB weight stage buffers
  char* Hc = smem + 32768;        // 128 KB: h1 rows; high halves = A park (GEMM1)
  float* Pp = (float*)smem;       // epilogue-2 partials (after pipeline drain)

  const int tid = threadIdx.x;
  const int wid = tid >> 6;
  const int lane = tid & 63;
  const int llo = lane & 15;
  const int lhi = lane >> 4;
  const int wr = wid & 1;
  const int wc = wid >> 1;
  const int m0 = blockIdx.x * BM;

  // A staging thread mapping: 8 consecutive f32 of one row
  const int arow = tid >> 2, ach = tid & 3;
  const float* aptr = feat + (size_t)(m0 + arow) * LATENT + ach * 8;
  const int a_st_base = (ach * 4 + (arow >> 5)) * 1024 + 512 + (((arow ^ (ach << 2)) & 31) << 4);

  // ---- prologue: stage(0) + aload(0) ----
  stage16(wsrc(W0pre, W1pre, 0), Wbuf, wid, lane);
  float4v a0 = *(const float4v*)(aptr);
  float4v a1 = *(const float4v*)(aptr + 4);

  f32x4 acc[4][4];
#pragma unroll
  for (int nt = 0; nt < 4; ++nt)
#pragma unroll
    for (int mt = 0; mt < 4; ++mt) acc[nt][mt] = 0.0f;
  float pacc[4][3];
#pragma unroll
  for (int mt = 0; mt < 4; ++mt) { pacc[mt][0] = 0.f; pacc[mt][1] = 0.f; pacc[mt][2] = 0.f; }

#pragma unroll 1
  for (int s = 0; s < NSTEPS; ++s) {
    const int cb = s & 1;
    const int nxt = (s + 1 < NSTEPS) ? s + 1 : NSTEPS - 1;  // dummy refetch at end
    stage16(wsrc(W0pre, W1pre, nxt), Wbuf + (cb ^ 1) * 16384, wid, lane);
    asm volatile("s_waitcnt vmcnt(2)" ::: "memory");  // stage(s)+aload(s) done; stage(s+1) flying
    if (s < 8) {
      unsigned u[4];
      u[0] = f2bf(a0[0]) | (f2bf(a0[1]) << 16);
      u[1] = f2bf(a0[2]) | (f2bf(a0[3]) << 16);
      u[2] = f2bf(a1[0]) | (f2bf(a1[1]) << 16);
      u[3] = f2bf(a1[2]) | (f2bf(a1[3]) << 16);
      *(int4v*)(Hc + s * 16384 + a_st_base) = *(int4v*)u;
      if (s < 7) {
        a0 = *(const float4v*)(aptr + (s + 1) * 32);
        a1 = *(const float4v*)(aptr + (s + 1) * 32 + 4);
      }
    }
    asm volatile("s_waitcnt lgkmcnt(0)\n\ts_barrier" ::: "memory");  // (a)

    const char* Wc = Wbuf + cb * 16384;
    short8 wf[4], xf[4];
#pragma unroll
    for (int nt = 0; nt < 4; ++nt)
      wf[nt] = *(const short8*)(Wc + lhi * 4096 + (wc * 64 + nt * 16 + llo) * 16);
    if (s < 16) {
      const int t = s & 7;
#pragma unroll
      for (int mt = 0; mt < 4; ++mt) {
        int mm = wr * 64 + mt * 16 + llo;
        xf[mt] = *(const short8*)(Hc + (t * 16 + lhi * 4 + (mm >> 5)) * 1024 + 512 +
                                  (((mm ^ (lhi << 2)) & 31) << 4));
      }
    } else {
      const int t = (s - 16) & 15;
#pragma unroll
      for (int mt = 0; mt < 4; ++mt) {
        int mm = wr * 64 + mt * 16 + llo;
        xf[mt] = *(const short8*)(Hc + mm * 1024 + ((t * 64 + lhi * 16) ^ (llo << 4)));
      }
    }
#pragma unroll
    for (int nt = 0; nt < 4; ++nt)
#pragma unroll
      for (int mt = 0; mt < 4; ++mt)
        acc[nt][mt] = __builtin_amdgcn_mfma_f32_16x16x32_bf16(wf[nt], xf[mt], acc[nt][mt], 0, 0, 0);
    asm volatile("s_waitcnt lgkmcnt(0)\n\ts_barrier" ::: "memory");  // (b): reads done

    if (s == 7 || s == 15) {
      // epilogue 1 (half hf): h1 = silu(acc + b0) -> Hc bytes [hf*512, hf*512+512)
      const int hf = (s >> 3) & 1;
#pragma unroll
      for (int nt = 0; nt < 4; ++nt) {
        int nb2 = wc * 64 + nt * 16 + lhi * 4;
        float4v bv = *(const float4v*)(b0 + hf * 256 + nb2);
#pragma unroll
        for (int mt = 0; mt < 4; ++mt) {
          int m = wr * 64 + mt * 16 + llo;
          uint2v pk;
          pk.x = f2bf(silu_f(acc[nt][mt][0] + bv[0])) | (f2bf(silu_f(acc[nt][mt][1] + bv[1])) << 16);
          pk.y = f2bf(silu_f(acc[nt][mt][2] + bv[2])) | (f2bf(silu_f(acc[nt][mt][3] + bv[3])) << 16);
          *(uint2v*)(Hc + m * 1024 + ((hf * 512 + nb2 * 2) ^ (llo << 4))) = pk;
        }
      }
#pragma unroll
      for (int nt = 0; nt < 4; ++nt)
#pragma unroll
        for (int mt = 0; mt < 4; ++mt) acc[nt][mt] = 0.0f;
    }
    if (s == 31 || s == 47) {
      // epilogue 2 partial (half hf): pacc += silu(acc + b1) @ W2 slice
      const int hf = ((s - 16) >> 4) & 1;
#pragma unroll
      for (int nt = 0; nt < 4; ++nt) {
        int nb2 = hf * 256 + wc * 64 + nt * 16 + lhi * 4;
        float4v bv = *(const float4v*)(b1 + nb2);
#pragma unroll
        for (int r = 0; r < 4; ++r) {
          float w20 = W2[(nb2 + r) * 3 + 0];
          float w21 = W2[(nb2 + r) * 3 + 1];
          float w22 = W2[(nb2 + r) * 3 + 2];
#pragma unroll
          for (int mt = 0; mt < 4; ++mt) {
            float h = silu_f(acc[nt][mt][r] + bv[r]);
            pacc[mt][0] += h * w20; pacc[mt][1] += h * w21; pacc[mt][2] += h * w22;
          }
        }
      }
#pragma unroll
      for (int nt = 0; nt < 4; ++nt)
#pragma unroll
        for (int mt = 0; mt < 4; ++mt) acc[nt][mt] = 0.0f;
    }
  }

  // drain pipeline, then reuse Wbuf as Pp
  asm volatile("s_waitcnt vmcnt(0) lgkmcnt(0)\n\ts_barrier" ::: "memory");
#pragma unroll
  for (int mt = 0; mt < 4; ++mt)
#pragma unroll
    for (int o = 0; o < 3; ++o) {
      float v = pacc[mt][o];
      v += __shfl_xor(v, 16);
      v += __shfl_xor(v, 32);
      if (lane < 16) Pp[wid * 192 + (mt * 16 + llo) * 3 + o] = v;
    }
  asm volatile("s_waitcnt lgkmcnt(0)\n\ts_barrier" ::: "memory");
  if (tid < 384) {
    int m = tid / 3, o = tid - m * 3;
    int wrr = m >> 6, ml = m & 63;
    float v = b2[o];
#pragma unroll
    for (int wcc = 0; wcc < 4; ++wcc) v += Pp[(wrr + 2 * wcc) * 192 + ml * 3 + o];
    pred[(size_t)(m0 + m) * 3 + o] = v;
  }
}

// ---------------------------------------------------------------------------
// Per-graph finalize: mean removal + analytic torque removal. 1 block/graph.
// ---------------------------------------------------------------------------
template<int NV>
__device__ __forceinline__ void block_reduce(const float* v, float (*sc)[16], int wid, int lane,
                                             float* tot) {
#pragma unroll
  for (int j = 0; j < NV; ++j) {
    float x = v[j];
#pragma unroll
    for (int off = 32; off >= 1; off >>= 1) x += __shfl_down(x, off);
    if (lane == 0) sc[wid][j] = x;
  }
  __syncthreads();
#pragma unroll
  for (int j = 0; j < NV; ++j) tot[j] = sc[0][j] + sc[1][j] + sc[2][j] + sc[3][j];
  __syncthreads();
}

__global__ __launch_bounds__(256) void finalize_kernel(
    const float* __restrict__ pred, const float* __restrict__ pos,
    const float* __restrict__ cell, const int* __restrict__ n_node,
    float* __restrict__ out) {
  __shared__ float sc[4][16];
  int g = blockIdx.x, tid = threadIdx.x;
  int wid = tid >> 6, lane = tid & 63;
  size_t i = (size_t)g * NPG + tid;

  float p0 = pred[i * 3 + 0], p1 = pred[i * 3 + 1], p2 = pred[i * 3 + 2];
  float q0 = pos[i * 3 + 0], q1 = pos[i * 3 + 1], q2 = pos[i * 3 + 2];

  float v1[6] = {p0, p1, p2, q0, q1, q2};
  float t1[6];
  block_reduce<6>(v1, sc, wid, lane, t1);

  float cnt = (float)n_node[g];
  float pc0 = p0 - t1[0] / cnt, pc1 = p1 - t1[1] / cnt, pc2 = p2 - t1[2] / cnt;
  float r0 = q0 - t1[3] / cnt, r1 = q1 - t1[4] / cnt, r2 = q2 - t1[5] / cnt;

  float v2[10] = {r1 * pc2 - r2 * pc1, r2 * pc0 - r0 * pc2, r0 * pc1 - r1 * pc0,
                  r0 * r0 + r1 * r1 + r2 * r2,
                  r0 * r0, r0 * r1, r0 * r2, r1 * r1, r1 * r2, r2 * r2};
  float t2[10];
  block_reduce<10>(v2, sc, wid, lane, t2);

  double s = (double)t2[3];
  double a = (double)t2[4] - s, b = (double)t2[5], c = (double)t2[6];
  double d = (double)t2[7] - s, e = (double)t2[8], f = (double)t2[9] - s;
  double A00 = d * f - e * e;
  double A01 = c * e - b * f;
  double A02 = b * e - c * d;
  double A11 = a * f - c * c;
  double A12 = b * c - a * e;
  double A22 = a * d - b * b;
  double det = a * A00 + b * A01 + c * A02;
  double rinv = 1.0 / det;
  double rhs0 = -(double)t2[0], rhs1 = -(double)t2[1], rhs2 = -(double)t2[2];
  double mu0 = (A00 * rhs0 + A01 * rhs1 + A02 * rhs2) * rinv;
  double mu1 = (A01 * rhs0 + A11 * rhs1 + A12 * rhs2) * rinv;
  double mu2 = (A02 * rhs0 + A12 * rhs1 + A22 * rhs2) * rinv;

  bool nopbc = true;
#pragma unroll
  for (int j = 0; j < 9; ++j) nopbc = nopbc && (cell[g * 9 + j] == 0.0f);

  float d0 = (float)((double)r1 * mu2 - (double)r2 * mu1);
  float d1 = (float)((double)r2 * mu0 - (double)r0 * mu2);
  float d2 = (float)((double)r0 * mu1 - (double)r1 * mu0);

  out[i * 3 + 0] = pc0 + (nopbc ? d0 : 0.0f);
  out[i * 3 + 1] = pc1 + (nopbc ? d1 : 0.0f);
  out[i * 3 + 2] = pc2 + (nopbc ? d2 : 0.0f);
}

// ---------------------------------------------------------------------------
extern "C" void kernel_launch(void* const* d_in, const int* in_sizes, int n_in,
                              void* d_out, int out_size, void* d_ws, size_t ws_size,
                              hipStream_t stream) {
  const float* feat = (const float*)d_in[0];
  const float* positions = (const float*)d_in[1];
  const float* cell = (const float*)d_in[2];
  const int* n_node = (const int*)d_in[3];
  const float* W0 = (const float*)d_in[4];
  const float* b0 = (const float*)d_in[5];
  const float* W1 = (const float*)d_in[6];
  const float* b1 = (const float*)d_in[7];
  const float* W2 = (const float*)d_in[8];
  const float* b2 = (const float*)d_in[9];
  float* out = (float*)d_out;

  char* ws = (char*)d_ws;
  ushort_t* W0pre = (ushort_t*)ws;                       // 256 KB
  ushort_t* W1pre = (ushort_t*)(ws + 262144);            // 512 KB
  float* pred = (float*)(ws + 786432);                   // 3 MB

  hipLaunchKernelGGL(prep_weights, dim3(192), dim3(256), 0, stream, W0, W1, W0pre, W1pre);
  hipLaunchKernelGGL(fused_mlp, dim3(N_NODES / BM), dim3(512), 0, stream,
                     feat, W0pre, W1pre, b0, b1, W2, b2, pred);
  hipLaunchKernelGGL(finalize_kernel, dim3(BGRAPHS), dim3(256), 0, stream, pred, positions, cell,
                     n_node, out);
}

// Round 5
// 340.347 us; speedup vs baseline: 1.2618x; 1.2618x over previous
//
#include <hip/hip_runtime.h>

#define N_NODES 262144
#define BGRAPHS 1024
#define NPG 256
#define LATENT 256
#define HIDDEN 512
#define BM 128

typedef unsigned short ushort_t;
typedef __attribute__((ext_vector_type(4))) float  f32x4;
typedef __attribute__((ext_vector_type(8))) short  short8;
typedef __attribute__((ext_vector_type(4))) int    int4v;
typedef __attribute__((ext_vector_type(2))) unsigned int uint2v;
typedef __attribute__((ext_vector_type(4))) float  float4v;

__device__ __forceinline__ unsigned int f2bf(float f) {
  union { float f; unsigned int u; } v; v.f = f;
  unsigned int u = v.u;
  return (u + 0x7fffu + ((u >> 16) & 1u)) >> 16;
}
__device__ __forceinline__ float silu_f(float x) { return x / (1.0f + __expf(-x)); }

// ---------------------------------------------------------------------------
// Weight prep: pre-tile W0/W1 (f32 [K][N]) into per-K-step fragment images:
// byte(kstep, p, n) = kstep*32768 + p*8192 + n*16, holding 8 bf16 of
// k = kstep*32 + p*8 .. +8 for column n. Read directly global->VGPR as MFMA
// fragments (lane(llo,lhi) of wave w: page p=lhi, n = w*64+nt*16+llo).
// ---------------------------------------------------------------------------
__global__ void prep_weights(const float* __restrict__ W0, const float* __restrict__ W1,
                             ushort_t* __restrict__ W0pre, ushort_t* __restrict__ W1pre) {
  int c = blockIdx.x * 256 + threadIdx.x;   // 49152 cells of 8 elems
  const int C0 = 16384;
  const float* src;
  ushort_t* dst;
  int cc;
  if (c < C0) { src = W0; dst = W0pre; cc = c; }
  else        { src = W1; dst = W1pre; cc = c - C0; }
  int kstep = cc >> 11;
  int p = (cc >> 9) & 3;
  int n = cc & 511;
  int kb = kstep * 32 + p * 8;
  unsigned w[4];
#pragma unroll
  for (int j = 0; j < 4; ++j) {
    unsigned lo = f2bf(src[(size_t)(kb + 2 * j) * HIDDEN + n]);
    unsigned hi = f2bf(src[(size_t)(kb + 2 * j + 1) * HIDDEN + n]);
    w[j] = lo | (hi << 16);
  }
  *(int4v*)(dst + (size_t)cc * 8) = *(int4v*)w;
}

// ---------------------------------------------------------------------------
// Fused MLP. M=128/block, N=512 full. 8 waves, wave tile 128m x 64n,
// acc[4][8]. W frags: global->VGPR, prefetched 1 step ahead (no W in LDS!).
// LDS: Hc 128KB = h1 rows; feat bf16 parked in high halves during GEMM1.
// Barrier-light: only prologue + GEMM1->GEMM2 transition + epilogue.
// ---------------------------------------------------------------------------
__global__ __launch_bounds__(512) void fused_mlp(
    const float* __restrict__ feat, const ushort_t* __restrict__ W0pre,
    const ushort_t* __restrict__ W1pre, const float* __restrict__ b0,
    const float* __restrict__ b1, const float* __restrict__ W2,
    const float* __restrict__ b2, float* __restrict__ pred) {
  __shared__ __align__(16) char Hc[131072];
  float* Pp = (float*)Hc;

  const int tid = threadIdx.x;
  const int wid = tid >> 6;
  const int lane = tid & 63;
  const int llo = lane & 15;
  const int lhi = lane >> 4;
  const int m0 = blockIdx.x * BM;
  const int nqb = wid * 64 + llo;

  // ---- wf prefetch for s=0 ----
  short8 wf[4];
#pragma unroll
  for (int nt = 0; nt < 4; ++nt)
    wf[nt] = *(const short8*)(W0pre + lhi * 4096 + (nqb + nt * 16) * 8);

  // ---- park A: feat block rows -> bf16 chunks in Hc high halves ----
  {
    const int m = tid >> 2, q = tid & 3;
    const float* ap = feat + (size_t)(m0 + m) * LATENT + q * 64;
#pragma unroll
    for (int j = 0; j < 2; ++j) {
      const int cch = 2 * q + j;
#pragma unroll
      for (int p = 0; p < 4; ++p) {
        float4v x = *(const float4v*)(ap + j * 32 + p * 8);
        float4v y = *(const float4v*)(ap + j * 32 + p * 8 + 4);
        unsigned u[4];
        u[0] = f2bf(x[0]) | (f2bf(x[1]) << 16);
        u[1] = f2bf(x[2]) | (f2bf(x[3]) << 16);
        u[2] = f2bf(y[0]) | (f2bf(y[1]) << 16);
        u[3] = f2bf(y[2]) | (f2bf(y[3]) << 16);
        *(int4v*)(Hc + ((cch * 16 + p * 4 + (m >> 5)) << 10) + 512 +
                  (((m & 31) ^ (p << 3)) << 4)) = *(int4v*)u;
      }
    }
  }
  __syncthreads();

  f32x4 acc[4][8];
#pragma unroll
  for (int nt = 0; nt < 4; ++nt)
#pragma unroll
    for (int mt = 0; mt < 8; ++mt) acc[nt][mt] = 0.0f;

#pragma unroll 1
  for (int s = 0; s < 24; ++s) {
    // prefetch next step's W fragments (global->reg, L2-resident)
    short8 wn[4];
    if (s < 23) {
      const ushort_t* wp = (s < 7) ? W0pre + (s + 1) * 16384 : W1pre + (s - 7) * 16384;
#pragma unroll
      for (int nt = 0; nt < 4; ++nt)
        wn[nt] = *(const short8*)(wp + lhi * 4096 + (nqb + nt * 16) * 8);
    }
    // A fragments from LDS
    short8 xf[8];
    if (s < 8) {
#pragma unroll
      for (int mt = 0; mt < 8; ++mt) {
        int mm = mt * 16 + llo;
        xf[mt] = *(const short8*)(Hc + ((s * 16 + lhi * 4 + (mm >> 5)) << 10) + 512 +
                                  (((mm & 31) ^ (lhi << 3)) << 4));
      }
    } else {
      const int t = s - 8;
#pragma unroll
      for (int mt = 0; mt < 8; ++mt) {
        int mm = mt * 16 + llo;
        xf[mt] = *(const short8*)(Hc + mm * 1024 + ((t * 64 + lhi * 16) ^ (llo << 4)));
      }
    }
    __builtin_amdgcn_s_setprio(1);
#pragma unroll
    for (int nt = 0; nt < 4; ++nt)
#pragma unroll
      for (int mt = 0; mt < 8; ++mt)
        acc[nt][mt] = __builtin_amdgcn_mfma_f32_16x16x32_bf16(wf[nt], xf[mt], acc[nt][mt], 0, 0, 0);
    __builtin_amdgcn_s_setprio(0);

    if (s == 7) {
      __syncthreads();  // all park reads done
      // epilogue 1: h1 = silu(acc + b0) -> Hc rows (swizzled), overwrites park
#pragma unroll
      for (int nt = 0; nt < 4; ++nt) {
        int nb = wid * 64 + nt * 16 + lhi * 4;
        float4v bv = *(const float4v*)(b0 + nb);
#pragma unroll
        for (int mt = 0; mt < 8; ++mt) {
          int m = mt * 16 + llo;
          uint2v pk;
          pk.x = f2bf(silu_f(acc[nt][mt][0] + bv[0])) | (f2bf(silu_f(acc[nt][mt][1] + bv[1])) << 16);
          pk.y = f2bf(silu_f(acc[nt][mt][2] + bv[2])) | (f2bf(silu_f(acc[nt][mt][3] + bv[3])) << 16);
          *(uint2v*)(Hc + m * 1024 + ((nb * 2) ^ (llo << 4))) = pk;
        }
      }
#pragma unroll
      for (int nt = 0; nt < 4; ++nt)
#pragma unroll
        for (int mt = 0; mt < 8; ++mt) acc[nt][mt] = 0.0f;
      __syncthreads();  // h1 visible to all waves
    }
    if (s < 23) {
#pragma unroll
      for (int nt = 0; nt < 4; ++nt) wf[nt] = wn[nt];
    }
  }

  // ---- epilogue 2: pacc = silu(acc + b1) @ W2 (registers only) ----
  float pacc[8][3];
#pragma unroll
  for (int mt = 0; mt < 8; ++mt) { pacc[mt][0] = 0.f; pacc[mt][1] = 0.f; pacc[mt][2] = 0.f; }
#pragma unroll
  for (int nt = 0; nt < 4; ++nt) {
    int nb = wid * 64 + nt * 16 + lhi * 4;
    float4v bv = *(const float4v*)(b1 + nb);
#pragma unroll
    for (int r = 0; r < 4; ++r) {
      float w20 = W2[(nb + r) * 3 + 0];
      float w21 = W2[(nb + r) * 3 + 1];
      float w22 = W2[(nb + r) * 3 + 2];
#pragma unroll
      for (int mt = 0; mt < 8; ++mt) {
        float h = silu_f(acc[nt][mt][r] + bv[r]);
        pacc[mt][0] += h * w20; pacc[mt][1] += h * w21; pacc[mt][2] += h * w22;
      }
    }
  }
  __syncthreads();  // all h1 reads done before Pp overlays Hc
#pragma unroll
  for (int mt = 0; mt < 8; ++mt)
#pragma unroll
    for (int o = 0; o < 3; ++o) {
      float v = pacc[mt][o];
      v += __shfl_xor(v, 16);
      v += __shfl_xor(v, 32);
      if (lane < 16) Pp[wid * 384 + (mt * 16 + llo) * 3 + o] = v;
    }
  __syncthreads();
  if (tid < 384) {
    int m = tid / 3, o = tid - m * 3;
    float v = b2[o];
#pragma unroll
    for (int ww = 0; ww < 8; ++ww) v += Pp[ww * 384 + m * 3 + o];
    pred[(size_t)(m0 + m) * 3 + o] = v;
  }
}

// ---------------------------------------------------------------------------
// Per-graph finalize: mean removal + analytic torque removal. 1 block/graph.
// ---------------------------------------------------------------------------
template<int NV>
__device__ __forceinline__ void block_reduce(const float* v, float (*sc)[16], int wid, int lane,
                                             float* tot) {
#pragma unroll
  for (int j = 0; j < NV; ++j) {
    float x = v[j];
#pragma unroll
    for (int off = 32; off >= 1; off >>= 1) x += __shfl_down(x, off);
    if (lane == 0) sc[wid][j] = x;
  }
  __syncthreads();
#pragma unroll
  for (int j = 0; j < NV; ++j) tot[j] = sc[0][j] + sc[1][j] + sc[2][j] + sc[3][j];
  __syncthreads();
}

__global__ __launch_bounds__(256) void finalize_kernel(
    const float* __restrict__ pred, const float* __restrict__ pos,
    const float* __restrict__ cell, const int* __restrict__ n_node,
    float* __restrict__ out) {
  __shared__ float sc[4][16];
  int g = blockIdx.x, tid = threadIdx.x;
  int wid = tid >> 6, lane = tid & 63;
  size_t i = (size_t)g * NPG + tid;

  float p0 = pred[i * 3 + 0], p1 = pred[i * 3 + 1], p2 = pred[i * 3 + 2];
  float q0 = pos[i * 3 + 0], q1 = pos[i * 3 + 1], q2 = pos[i * 3 + 2];

  float v1[6] = {p0, p1, p2, q0, q1, q2};
  float t1[6];
  block_reduce<6>(v1, sc, wid, lane, t1);

  float cnt = (float)n_node[g];
  float pc0 = p0 - t1[0] / cnt, pc1 = p1 - t1[1] / cnt, pc2 = p2 - t1[2] / cnt;
  float r0 = q0 - t1[3] / cnt, r1 = q1 - t1[4] / cnt, r2 = q2 - t1[5] / cnt;

  float v2[10] = {r1 * pc2 - r2 * pc1, r2 * pc0 - r0 * pc2, r0 * pc1 - r1 * pc0,
                  r0 * r0 + r1 * r1 + r2 * r2,
                  r0 * r0, r0 * r1, r0 * r2, r1 * r1, r1 * r2, r2 * r2};
  float t2[10];
  block_reduce<10>(v2, sc, wid, lane, t2);

  double s = (double)t2[3];
  double a = (double)t2[4] - s, b = (double)t2[5], c = (double)t2[6];
  double d = (double)t2[7] - s, e = (double)t2[8], f = (double)t2[9] - s;
  double A00 = d * f - e * e;
  double A01 = c * e - b * f;
  double A02 = b * e - c * d;
  double A11 = a * f - c * c;
  double A12 = b * c - a * e;
  double A22 = a * d - b * b;
  double det = a * A00 + b * A01 + c * A02;
  double rinv = 1.0 / det;
  double rhs0 = -(double)t2[0], rhs1 = -(double)t2[1], rhs2 = -(double)t2[2];
  double mu0 = (A00 * rhs0 + A01 * rhs1 + A02 * rhs2) * rinv;
  double mu1 = (A01 * rhs0 + A11 * rhs1 + A12 * rhs2) * rinv;
  double mu2 = (A02 * rhs0 + A12 * rhs1 + A22 * rhs2) * rinv;

  bool nopbc = true;
#pragma unroll
  for (int j = 0; j < 9; ++j) nopbc = nopbc && (cell[g * 9 + j] == 0.0f);

  float d0 = (float)((double)r1 * mu2 - (double)r2 * mu1);
  float d1 = (float)((double)r2 * mu0 - (double)r0 * mu2);
  float d2 = (float)((double)r0 * mu1 - (double)r1 * mu0);

  out[i * 3 + 0] = pc0 + (nopbc ? d0 : 0.0f);
  out[i * 3 + 1] = pc1 + (nopbc ? d1 : 0.0f);
  out[i * 3 + 2] = pc2 + (nopbc ? d2 : 0.0f);
}

// ---------------------------------------------------------------------------
extern "C" void kernel_launch(void* const* d_in, const int* in_sizes, int n_in,
                              void* d_out, int out_size, void* d_ws, size_t ws_size,
                              hipStream_t stream) {
  const float* feat = (const float*)d_in[0];
  const float* positions = (const float*)d_in[1];
  const float* cell = (const float*)d_in[2];
  const int* n_node = (const int*)d_in[3];
  const float* W0 = (const float*)d_in[4];
  const float* b0 = (const float*)d_in[5];
  const float* W1 = (const float*)d_in[6];
  const float* b1 = (const float*)d_in[7];
  const float* W2 = (const float*)d_in[8];
  const float* b2 = (const float*)d_in[9];
  float* out = (float*)d_out;

  char* ws = (char*)d_ws;
  ushort_t* W0pre = (ushort_t*)ws;                       // 256 KB
  ushort_t* W1pre = (ushort_t*)(ws + 262144);            // 512 KB
  float* pred = (float*)(ws + 786432);                   // 3 MB

  hipLaunchKernelGGL(prep_weights, dim3(192), dim3(256), 0, stream, W0, W1, W0pre, W1pre);
  hipLaunchKernelGGL(fused_mlp, dim3(N_NODES / BM), dim3(512), 0, stream,
                     feat, W0pre, W1pre, b0, b1, W2, b2, pred);
  hipLaunchKernelGGL(finalize_kernel, dim3(BGRAPHS), dim3(256), 0, stream, pred, positions, cell,
                     n_node, out);
}

// Round 6
// 248.522 us; speedup vs baseline: 1.7280x; 1.3695x over previous
//
#include <hip/hip_runtime.h>

#define N_NODES 262144
#define BGRAPHS 1024
#define NPG 256
#define LATENT 256
#define HIDDEN 512
#define BM 128

typedef unsigned short ushort_t;
typedef __attribute__((ext_vector_type(4))) float  f32x4;
typedef __attribute__((ext_vector_type(8))) short  short8;
typedef __attribute__((ext_vector_type(4))) int    int4v;
typedef __attribute__((ext_vector_type(2))) unsigned int uint2v;
typedef __attribute__((ext_vector_type(4))) float  float4v;

__device__ __forceinline__ unsigned int f2bf(float f) {
  union { float f; unsigned int u; } v; v.f = f;
  unsigned int u = v.u;
  return (u + 0x7fffu + ((u >> 16) & 1u)) >> 16;
}
__device__ __forceinline__ unsigned int cvtpk(float lo, float hi) {
  unsigned int r;
  asm("v_cvt_pk_bf16_f32 %0, %1, %2" : "=v"(r) : "v"(lo), "v"(hi));
  return r;
}
__device__ __forceinline__ float silu_f(float x) {
  return x * __builtin_amdgcn_rcpf(1.0f + __expf(-x));
}

// ---------------------------------------------------------------------------
// Weight prep: pre-tile W0/W1 (f32 [K][N]) into per-K-step fragment images:
// byte(kstep,p,n) = kstep*32768 + p*8192 + n*16 (8 bf16: k=kstep*32+p*8..+8,
// col n). W0pre (8 steps) and W1pre (16 steps) are CONTIGUOUS in ws ->
// one 24-step stream.
// ---------------------------------------------------------------------------
__global__ void prep_weights(const float* __restrict__ W0, const float* __restrict__ W1,
                             ushort_t* __restrict__ W0pre, ushort_t* __restrict__ W1pre) {
  int c = blockIdx.x * 256 + threadIdx.x;   // 49152 cells of 8 elems
  const int C0 = 16384;
  const float* src;
  ushort_t* dst;
  int cc;
  if (c < C0) { src = W0; dst = W0pre; cc = c; }
  else        { src = W1; dst = W1pre; cc = c - C0; }
  int kstep = cc >> 11;
  int p = (cc >> 9) & 3;
  int n = cc & 511;
  int kb = kstep * 32 + p * 8;
  unsigned w[4];
#pragma unroll
  for (int j = 0; j < 4; ++j) {
    unsigned lo = f2bf(src[(size_t)(kb + 2 * j) * HIDDEN + n]);
    unsigned hi = f2bf(src[(size_t)(kb + 2 * j + 1) * HIDDEN + n]);
    w[j] = lo | (hi << 16);
  }
  *(int4v*)(dst + (size_t)cc * 8) = *(int4v*)w;
}

// ---------------------------------------------------------------------------
// Fused MLP. M=128/block, N=512 full. 8 waves, wave tile 128m x 64n,
// acc[4][8]. W frags: global->VGPR ping-pong prefetch (no W in LDS).
// LDS: Hc 128KB = h1 rows; feat bf16 parked in high halves during GEMM1.
// ---------------------------------------------------------------------------
__global__ __launch_bounds__(512) void fused_mlp(
    const float* __restrict__ feat, const ushort_t* __restrict__ W0pre,
    const ushort_t* __restrict__ W1pre, const float* __restrict__ b0,
    const float* __restrict__ b1, const float* __restrict__ W2,
    const float* __restrict__ b2, float* __restrict__ pred) {
  __shared__ __align__(16) char Hc[131072];
  float* Pp = (float*)Hc;

  const int tid = threadIdx.x;
  const int wid = tid >> 6;
  const int lane = tid & 63;
  const int llo = lane & 15;
  const int lhi = lane >> 4;
  const int m0 = blockIdx.x * BM;

  // per-thread weight fragment base: + step*32768 + nt*256
  const char* wp = (const char*)W0pre + lhi * 8192 + (wid * 64 + llo) * 16;
  short8 wf0[4], wf1[4];
#pragma unroll
  for (int nt = 0; nt < 4; ++nt) wf0[nt] = *(const short8*)(wp + nt * 256);

  // ---- park A: feat block rows -> bf16 chunks in Hc high halves ----
  {
    const int m = tid >> 2, q = tid & 3;
    const float* ap = feat + (size_t)(m0 + m) * LATENT + q * 64;
#pragma unroll
    for (int j = 0; j < 2; ++j) {
      const int cch = 2 * q + j;
#pragma unroll
      for (int p = 0; p < 4; ++p) {
        float4v x = *(const float4v*)(ap + j * 32 + p * 8);
        float4v y = *(const float4v*)(ap + j * 32 + p * 8 + 4);
        unsigned u[4];
        u[0] = cvtpk(x[0], x[1]);
        u[1] = cvtpk(x[2], x[3]);
        u[2] = cvtpk(y[0], y[1]);
        u[3] = cvtpk(y[2], y[3]);
        *(int4v*)(Hc + ((cch * 16 + p * 4 + (m >> 5)) << 10) + 512 +
                  (((m & 31) ^ (p << 3)) << 4)) = *(int4v*)u;
      }
    }
  }
  __syncthreads();

  f32x4 acc[4][8];
#pragma unroll
  for (int nt = 0; nt < 4; ++nt)
#pragma unroll
    for (int mt = 0; mt < 8; ++mt) acc[nt][mt] = 0.0f;

  // GEMM1 A-frag addressing: base + s*16384 + (mt>>1)*1024 + (mt&1 ? xo : xe)
  const char* ab = Hc + lhi * 4096 + 512;
  const int xe = ((llo ^ (lhi << 3)) << 4);
  const int xo = (((16 + llo) ^ (lhi << 3)) << 4);

#define MFMA_ALL(WF, XF)                                                                 \
  __builtin_amdgcn_s_setprio(1);                                                         \
  _Pragma("unroll") for (int nt = 0; nt < 4; ++nt)                                       \
  _Pragma("unroll") for (int mt = 0; mt < 8; ++mt)                                       \
      acc[nt][mt] = __builtin_amdgcn_mfma_f32_16x16x32_bf16(WF[nt], XF[mt], acc[nt][mt], \
                                                            0, 0, 0);                    \
  __builtin_amdgcn_s_setprio(0);

#define G1_STEP(SOFF, WA, WB)                                                            \
  {                                                                                      \
    _Pragma("unroll") for (int nt = 0; nt < 4; ++nt)                                     \
        WB[nt] = *(const short8*)(wpp + 32768 + (SOFF) * 32768 + nt * 256);              \
    short8 xf[8];                                                                        \
    _Pragma("unroll") for (int mt = 0; mt < 8; ++mt)                                     \
        xf[mt] = *(const short8*)(abp + (SOFF) * 16384 + ((mt >> 1) << 10) +             \
                                  ((mt & 1) ? xo : xe));                                 \
    MFMA_ALL(WA, xf)                                                                     \
  }

  // ================= GEMM1: 8 K-steps =================
  {
    const char* wpp = wp;
    const char* abp = ab;
#pragma unroll 1
    for (int s = 0; s < 8; s += 2) {
      G1_STEP(0, wf0, wf1)
      G1_STEP(1, wf1, wf0)
      wpp += 65536;
      abp += 32768;
    }
  }

  // ---- epilogue 1: h1 = silu(acc + b0) -> Hc rows (swizzled) ----
  __syncthreads();  // all park reads done
#pragma unroll
  for (int nt = 0; nt < 4; ++nt) {
    int nb = wid * 64 + nt * 16 + lhi * 4;
    float4v bv = *(const float4v*)(b0 + nb);
#pragma unroll
    for (int mt = 0; mt < 8; ++mt) {
      int m = mt * 16 + llo;
      float s0 = silu_f(acc[nt][mt][0] + bv[0]);
      float s1 = silu_f(acc[nt][mt][1] + bv[1]);
      float s2 = silu_f(acc[nt][mt][2] + bv[2]);
      float s3 = silu_f(acc[nt][mt][3] + bv[3]);
      uint2v pk;
      pk.x = cvtpk(s0, s1);
      pk.y = cvtpk(s2, s3);
      *(uint2v*)(Hc + m * 1024 + ((nb * 2) ^ (llo << 4))) = pk;
    }
  }
#pragma unroll
  for (int nt = 0; nt < 4; ++nt)
#pragma unroll
    for (int mt = 0; mt < 8; ++mt) acc[nt][mt] = 0.0f;
  __syncthreads();  // h1 visible to all waves

#define G2_STEP(T, WA, WB)                                                               \
  {                                                                                      \
    if ((T) < 15) {                                                                      \
      _Pragma("unroll") for (int nt = 0; nt < 4; ++nt)                                   \
          WB[nt] = *(const short8*)(wpp + 32768 + ((T)&1) * 32768 + nt * 256);           \
    }                                                                                    \
    const int col = (((T) * 64 + lhi * 16) ^ (llo << 4));                                \
    short8 xf[8];                                                                        \
    _Pragma("unroll") for (int mt = 0; mt < 8; ++mt)                                     \
        xf[mt] = *(const short8*)(Hc + (mt * 16 + llo) * 1024 + col);                    \
    MFMA_ALL(WA, xf)                                                                     \
  }

  // ================= GEMM2: 16 K-steps =================
  {
    const char* wpp = wp + 8 * 32768;
#pragma unroll 1
    for (int t = 0; t < 16; t += 2) {
      G2_STEP(t, wf0, wf1)
      G2_STEP(t + 1, wf1, wf0)
      wpp += 65536;
    }
  }

  // ---- epilogue 2: pacc = silu(acc + b1) @ W2 (registers only) ----
  float pacc[8][3];
#pragma unroll
  for (int mt = 0; mt < 8; ++mt) { pacc[mt][0] = 0.f; pacc[mt][1] = 0.f; pacc[mt][2] = 0.f; }
#pragma unroll
  for (int nt = 0; nt < 4; ++nt) {
    int nb = wid * 64 + nt * 16 + lhi * 4;
    float4v bv = *(const float4v*)(b1 + nb);
#pragma unroll
    for (int r = 0; r < 4; ++r) {
      float w20 = W2[(nb + r) * 3 + 0];
      float w21 = W2[(nb + r) * 3 + 1];
      float w22 = W2[(nb + r) * 3 + 2];
#pragma unroll
      for (int mt = 0; mt < 8; ++mt) {
        float h = silu_f(acc[nt][mt][r] + bv[r]);
        pacc[mt][0] += h * w20; pacc[mt][1] += h * w21; pacc[mt][2] += h * w22;
      }
    }
  }
  __syncthreads();  // all h1 reads done before Pp overlays Hc
#pragma unroll
  for (int mt = 0; mt < 8; ++mt)
#pragma unroll
    for (int o = 0; o < 3; ++o) {
      float v = pacc[mt][o];
      v += __shfl_xor(v, 16);
      v += __shfl_xor(v, 32);
      if (lane < 16) Pp[wid * 384 + (mt * 16 + llo) * 3 + o] = v;
    }
  __syncthreads();
  if (tid < 384) {
    int m = tid / 3, o = tid - m * 3;
    float v = b2[o];
#pragma unroll
    for (int ww = 0; ww < 8; ++ww) v += Pp[ww * 384 + m * 3 + o];
    pred[(size_t)(m0 + m) * 3 + o] = v;
  }
}

// ---------------------------------------------------------------------------
// Per-graph finalize: mean removal + analytic torque removal. 1 block/graph.
// ---------------------------------------------------------------------------
template<int NV>
__device__ __forceinline__ void block_reduce(const float* v, float (*sc)[16], int wid, int lane,
                                             float* tot) {
#pragma unroll
  for (int j = 0; j < NV; ++j) {
    float x = v[j];
#pragma unroll
    for (int off = 32; off >= 1; off >>= 1) x += __shfl_down(x, off);
    if (lane == 0) sc[wid][j] = x;
  }
  __syncthreads();
#pragma unroll
  for (int j = 0; j < NV; ++j) tot[j] = sc[0][j] + sc[1][j] + sc[2][j] + sc[3][j];
  __syncthreads();
}

__global__ __launch_bounds__(256) void finalize_kernel(
    const float* __restrict__ pred, const float* __restrict__ pos,
    const float* __restrict__ cell, const int* __restrict__ n_node,
    float* __restrict__ out) {
  __shared__ float sc[4][16];
  int g = blockIdx.x, tid = threadIdx.x;
  int wid = tid >> 6, lane = tid & 63;
  size_t i = (size_t)g * NPG + tid;

  float p0 = pred[i * 3 + 0], p1 = pred[i * 3 + 1], p2 = pred[i * 3 + 2];
  float q0 = pos[i * 3 + 0], q1 = pos[i * 3 + 1], q2 = pos[i * 3 + 2];

  float v1[6] = {p0, p1, p2, q0, q1, q2};
  float t1[6];
  block_reduce<6>(v1, sc, wid, lane, t1);

  float cnt = (float)n_node[g];
  float pc0 = p0 - t1[0] / cnt, pc1 = p1 - t1[1] / cnt, pc2 = p2 - t1[2] / cnt;
  float r0 = q0 - t1[3] / cnt, r1 = q1 - t1[4] / cnt, r2 = q2 - t1[5] / cnt;

  float v2[10] = {r1 * pc2 - r2 * pc1, r2 * pc0 - r0 * pc2, r0 * pc1 - r1 * pc0,
                  r0 * r0 + r1 * r1 + r2 * r2,
                  r0 * r0, r0 * r1, r0 * r2, r1 * r1, r1 * r2, r2 * r2};
  float t2[10];
  block_reduce<10>(v2, sc, wid, lane, t2);

  double s = (double)t2[3];
  double a = (double)t2[4] - s, b = (double)t2[5], c = (double)t2[6];
  double d = (double)t2[7] - s, e = (double)t2[8], f = (double)t2[9] - s;
  double A00 = d * f - e * e;
  double A01 = c * e - b * f;
  double A02 = b * e - c * d;
  double A11 = a * f - c * c;
  double A12 = b * c - a * e;
  double A22 = a * d - b * b;
  double det = a * A00 + b * A01 + c * A02;
  double rinv = 1.0 / det;
  double rhs0 = -(double)t2[0], rhs1 = -(double)t2[1], rhs2 = -(double)t2[2];
  double mu0 = (A00 * rhs0 + A01 * rhs1 + A02 * rhs2) * rinv;
  double mu1 = (A01 * rhs0 + A11 * rhs1 + A12 * rhs2) * rinv;
  double mu2 = (A02 * rhs0 + A12 * rhs1 + A22 * rhs2) * rinv;

  bool nopbc = true;
#pragma unroll
  for (int j = 0; j < 9; ++j) nopbc = nopbc && (cell[g * 9 + j] == 0.0f);

  float d0 = (float)((double)r1 * mu2 - (double)r2 * mu1);
  float d1 = (float)((double)r2 * mu0 - (double)r0 * mu2);
  float d2 = (float)((double)r0 * mu1 - (double)r1 * mu0);

  out[i * 3 + 0] = pc0 + (nopbc ? d0 : 0.0f);
  out[i * 3 + 1] = pc1 + (nopbc ? d1 : 0.0f);
  out[i * 3 + 2] = pc2 + (nopbc ? d2 : 0.0f);
}

// ---------------------------------------------------------------------------
extern "C" void kernel_launch(void* const* d_in, const int* in_sizes, int n_in,
                              void* d_out, int out_size, void* d_ws, size_t ws_size,
                              hipStream_t stream) {
  const float* feat = (const float*)d_in[0];
  const float* positions = (const float*)d_in[1];
  const float* cell = (const float*)d_in[2];
  const int* n_node = (const int*)d_in[3];
  const float* W0 = (const float*)d_in[4];
  const float* b0 = (const float*)d_in[5];
  const float* W1 = (const float*)d_in[6];
  const float* b1 = (const float*)d_in[7];
  const float* W2 = (const float*)d_in[8];
  const float* b2 = (const float*)d_in[9];
  float* out = (float*)d_out;

  char* ws = (char*)d_ws;
  ushort_t* W0pre = (ushort_t*)ws;                       // 256 KB (8 steps)
  ushort_t* W1pre = (ushort_t*)(ws + 262144);            // 512 KB (16 steps, contiguous)
  float* pred = (float*)(ws + 786432);                   // 3 MB

  hipLaunchKernelGGL(prep_weights, dim3(192), dim3(256), 0, stream, W0, W1, W0pre, W1pre);
  hipLaunchKernelGGL(fused_mlp, dim3(N_NODES / BM), dim3(512), 0, stream,
                     feat, W0pre, W1pre, b0, b1, W2, b2, pred);
  hipLaunchKernelGGL(finalize_kernel, dim3(BGRAPHS), dim3(256), 0, stream, pred, positions, cell,
                     n_node, out);
}